// Round 4
// baseline (211.849 us; speedup 1.0000x reference)
//
#include <hip/hip_runtime.h>
#include <type_traits>

#define LMAX 24

typedef float f32x4 __attribute__((ext_vector_type(4)));

// ---------- compile-time normalization table K(l,m) ----------
constexpr double csqrt_(double x) {
  double y = x > 1.0 ? x : 1.0;
  for (int i = 0; i < 300; ++i) y = 0.5 * (y + x / y);
  return y;
}
constexpr double cfact_(int n) {
  double r = 1.0;
  for (int i = 2; i <= n; ++i) r *= (double)i;
  return r;
}
constexpr double PI_ = 3.14159265358979323846;

struct KTab {
  float k[LMAX][LMAX];
  constexpr KTab() : k{} {
    for (int l = 0; l < LMAX; ++l)
      for (int m = 0; m <= l; ++m)
        k[l][m] = (float)csqrt_((2.0 * l + 1.0) * cfact_(l - m) /
                                (4.0 * PI_ * cfact_(l + m)));
  }
};
constexpr KTab KT{};
constexpr float SQRT2_ = 1.41421356237309504880f;

// ---------- compile-time loop unroller ----------
template <int N, int I = 0, typename F>
__device__ __forceinline__ void static_for(F&& f) {
  if constexpr (I < N) {
    f(std::integral_constant<int, I>{});
    static_for<N, I + 1>(f);
  }
}

// 4 lanes per point. Each group of 4 lanes computes the full recurrence
// redundantly; lane slot s = tid&3 keeps j in [16c+4s, 16c+4s+4) and stores
// dwordx4 straight from registers -> per store instruction the wave writes
// 16 points x 64B = 16 full aligned cache lines. No LDS, no barriers.
template <bool GUARDED>
__global__ __launch_bounds__(256) void sh_kernel(const float* __restrict__ rd,
                                                 float* __restrict__ out,
                                                 int base, int n) {
  const int tid = threadIdx.x;
  const int slot = tid & 3;
  const int pt = base + blockIdx.x * 64 + (tid >> 2);
  const bool ptok = pt < n;
  const int src = ptok ? pt : 0;

  const float2 p = reinterpret_cast<const float2*>(rd)[src];
  const float D2R = 0.017453292519943295f;
  float phi = p.x * D2R;
  float theta = (p.y + 90.0f) * D2R;
  float x = cosf(theta);
  float somx2 = sqrtf((1.0f - x) * (1.0f + x));

  // cos(m*phi), sin(m*phi) via Chebyshev recurrence (register arrays)
  float cm[LMAX], sm[LMAX];
  cm[0] = 1.0f; sm[0] = 0.0f;
  float c1, s1;
  __sincosf(phi, &s1, &c1);
  cm[1] = c1; sm[1] = s1;
  float twoc = 2.0f * c1;
#pragma unroll
  for (int m = 2; m < LMAX; ++m) {
    cm[m] = twoc * cm[m - 1] - cm[m - 2];
    sm[m] = twoc * sm[m - 1] - sm[m - 2];
  }

  // slot-select masks (cndmask operands, computed once)
  const bool k0 = (slot == 0), k1 = (slot == 1), k2 = (slot == 2), k3 = (slot == 3);

  float cur[LMAX], prev[LMAX];
  float pmm = 1.0f;
  float b0 = 0.f, b1 = 0.f, b2 = 0.f, b3 = 0.f;

  // this lane's store base: row of its point, offset by its 4-dword slot
  float* const rowp = out + (size_t)pt * (LMAX * LMAX) + slot * 4;

  static_for<LMAX>([&](auto LC) {
    constexpr int l = decltype(LC)::value;

    // advance recurrence state for all m < l  (gives P(l,m))
    static_for<l>([&](auto MC) {
      constexpr int m = decltype(MC)::value;
      constexpr float a = (float)(2 * l - 1);
      constexpr float b = (float)(l + m - 1);
      constexpr float inv = 1.0f / (float)(l - m);
      float nxt = (a * x * cur[m] - b * prev[m]) * inv;
      prev[m] = cur[m];
      cur[m] = nxt;
    });

    // init state for m = l:  P(l,l) = pmm,  prev = 0
    if constexpr (l > 0) {
      pmm = pmm * (-(float)(2 * l - 1)) * somx2;
    }
    cur[l] = pmm;
    prev[l] = 0.0f;

    // emit row l in j order (j = l*l + l + m, globally contiguous 0..575).
    // every lane evaluates every y; keeps its slot's slice via cndmask;
    // store dwordx4 every 16 j's (address = rowp + 64B*c, immediate-foldable)
    static_for<2 * l + 1>([&](auto KC) {
      constexpr int m = decltype(KC)::value - l;
      constexpr int am = m < 0 ? -m : m;
      constexpr int j = l * l + l + m;
      constexpr float C = (m == 0) ? KT.k[l][0] : SQRT2_ * KT.k[l][am];
      float y;
      if constexpr (m == 0) {
        y = C * cur[0];
      } else if constexpr (m > 0) {
        y = C * (cm[am] * cur[am]);
      } else {
        y = C * (sm[am] * cur[am]);
      }
      constexpr int q = j & 3;          // position within the 4-dword slice
      constexpr int X = (j >> 2) & 3;   // which slot owns this y
      const bool kX = (X == 0) ? k0 : (X == 1) ? k1 : (X == 2) ? k2 : k3;
      if constexpr (q == 0) b0 = kX ? y : b0;
      if constexpr (q == 1) b1 = kX ? y : b1;
      if constexpr (q == 2) b2 = kX ? y : b2;
      if constexpr (q == 3) b3 = kX ? y : b3;
      if constexpr ((j & 15) == 15) {
        if constexpr (GUARDED) {
          if (ptok)
            *reinterpret_cast<f32x4*>(rowp + (j - 15)) = f32x4{b0, b1, b2, b3};
        } else {
          *reinterpret_cast<f32x4*>(rowp + (j - 15)) = f32x4{b0, b1, b2, b3};
        }
      }
    });
  });
}

extern "C" void kernel_launch(void* const* d_in, const int* in_sizes, int n_in,
                              void* d_out, int out_size, void* d_ws, size_t ws_size,
                              hipStream_t stream) {
  (void)n_in; (void)out_size; (void)d_ws; (void)ws_size;
  const float* rd = (const float*)d_in[0];
  float* out = (float*)d_out;
  int n = in_sizes[0] / 2;
  int full_blocks = n >> 6;             // 64 points per 256-thread block
  if (full_blocks > 0)
    sh_kernel<false><<<full_blocks, 256, 0, stream>>>(rd, out, 0, n);
  if (n & 63)
    sh_kernel<true><<<1, 256, 0, stream>>>(rd, out, full_blocks << 6, n);
}

// Round 5
// 193.520 us; speedup vs baseline: 1.0947x; 1.0947x over previous
//
#include <hip/hip_runtime.h>
#include <type_traits>

#define LMAX 24

typedef float f32x4 __attribute__((ext_vector_type(4)));

// ---------- compile-time normalization table K(l,m) ----------
constexpr double csqrt_(double x) {
  double y = x > 1.0 ? x : 1.0;
  for (int i = 0; i < 300; ++i) y = 0.5 * (y + x / y);
  return y;
}
constexpr double cfact_(int n) {
  double r = 1.0;
  for (int i = 2; i <= n; ++i) r *= (double)i;
  return r;
}
constexpr double PI_ = 3.14159265358979323846;

struct KTab {
  float k[LMAX][LMAX];
  constexpr KTab() : k{} {
    for (int l = 0; l < LMAX; ++l)
      for (int m = 0; m <= l; ++m)
        k[l][m] = (float)csqrt_((2.0 * l + 1.0) * cfact_(l - m) /
                                (4.0 * PI_ * cfact_(l + m)));
  }
};
constexpr KTab KT{};
constexpr float SQRT2_ = 1.41421356237309504880f;

// ---------- compile-time loop unroller ----------
template <int N, int I = 0, typename F>
__device__ __forceinline__ void static_for(F&& f) {
  if constexpr (I < N) {
    f(std::integral_constant<int, I>{});
    static_for<N, I + 1>(f);
  }
}

// One wave (64 threads) per block, 64 points per block. Staging buffer
// [64 points][32 j], row stride 33 dwords:
//   write bank = (lane + j) % 32      -> 2-way (free)
//   flush read bank = (8t + r + 4c)%32-> uniform 2-way (free)  [STR=33: 264%32=8]
// Small blocks give fine-grained scheduling: ~24 blocks/CU -> tiny drain tail
// (R2's 33KB/4-wave blocks had ~30us of end-of-kernel imbalance).
#define CJ 32
#define STR 33

__global__ __launch_bounds__(64) void sh_kernel(const float* __restrict__ rd,
                                                float* __restrict__ out, int n) {
  __shared__ float lds[64 * STR];

  const int lane = threadIdx.x;
  const long long base_pt = (long long)blockIdx.x * 64;
  const long long my_pt = base_pt + lane;
  const int src = my_pt < n ? (int)my_pt : 0;
  const bool full = (base_pt + 64) <= (long long)n;  // wave-uniform

  const float2 p = reinterpret_cast<const float2*>(rd)[src];
  const float D2R = 0.017453292519943295f;
  float phi = p.x * D2R;
  float theta = (p.y + 90.0f) * D2R;
  float x = cosf(theta);
  float somx2 = sqrtf((1.0f - x) * (1.0f + x));

  // cos(m*phi), sin(m*phi) via Chebyshev recurrence (register arrays)
  float cm[LMAX], sm[LMAX];
  cm[0] = 1.0f; sm[0] = 0.0f;
  float c1, s1;
  __sincosf(phi, &s1, &c1);
  cm[1] = c1; sm[1] = s1;
  float twoc = 2.0f * c1;
#pragma unroll
  for (int m = 2; m < LMAX; ++m) {
    cm[m] = twoc * cm[m - 1] - cm[m - 2];
    sm[m] = twoc * sm[m - 1] - sm[m - 2];
  }

  float cur[LMAX], prev[LMAX];
  float pmm = 1.0f;

  float* const wptr = lds + lane * STR;  // this thread's staging row
  const float* const rbase = lds;

  // cooperative flush of chunk jc (32 j-values for all 64 points)
  auto flush = [&](int jc) {
    __builtin_amdgcn_wave_barrier();
    if (full) {
#pragma unroll
      for (int t = 0; t < 8; ++t) {
        int pp = t * 8 + (lane >> 3);
        int off = pp * STR + (lane & 7) * 4;
        f32x4 v = *reinterpret_cast<const f32x4*>(rbase + off);
        *reinterpret_cast<f32x4*>(out + (base_pt + pp) * (size_t)(LMAX * LMAX) +
                                  jc * CJ + (lane & 7) * 4) = v;
      }
    } else {
#pragma unroll
      for (int t = 0; t < 8; ++t) {
        int pp = t * 8 + (lane >> 3);
        int off = pp * STR + (lane & 7) * 4;
        f32x4 v = *reinterpret_cast<const f32x4*>(rbase + off);
        long long pt = base_pt + pp;
        if (pt < n) {
          *reinterpret_cast<f32x4*>(out + pt * (size_t)(LMAX * LMAX) +
                                    jc * CJ + (lane & 7) * 4) = v;
        }
      }
    }
    __builtin_amdgcn_wave_barrier();
  };

  static_for<LMAX>([&](auto LC) {
    constexpr int l = decltype(LC)::value;

    // advance recurrence state for all m < l  (gives P(l,m))
    const float ax = (float)(2 * l - 1) * x;
    static_for<l>([&](auto MC) {
      constexpr int m = decltype(MC)::value;
      constexpr float b = (float)(l + m - 1);
      constexpr float inv = 1.0f / (float)(l - m);
      float nxt = (ax * cur[m] - b * prev[m]) * inv;
      prev[m] = cur[m];
      cur[m] = nxt;
    });

    // init state for m = l:  P(l,l) = pmm,  prev = 0
    if constexpr (l > 0) {
      pmm = pmm * (-(float)(2 * l - 1)) * somx2;
    }
    cur[l] = pmm;
    prev[l] = 0.0f;

    // emit row l in j order (j = l*l + l + m, globally contiguous 0..575),
    // staging into LDS; flush every 32 values
    static_for<2 * l + 1>([&](auto KC) {
      constexpr int m = decltype(KC)::value - l;
      constexpr int am = m < 0 ? -m : m;
      constexpr int j = l * l + l + m;
      constexpr float C = (m == 0) ? KT.k[l][0] : SQRT2_ * KT.k[l][am];
      float y;
      if constexpr (m == 0) {
        y = C * cur[0];
      } else if constexpr (m > 0) {
        y = C * (cm[am] * cur[am]);
      } else {
        y = C * (sm[am] * cur[am]);
      }
      wptr[j & (CJ - 1)] = y;
      if constexpr ((j & (CJ - 1)) == CJ - 1) {
        flush(j >> 5);
      }
    });
  });
}

extern "C" void kernel_launch(void* const* d_in, const int* in_sizes, int n_in,
                              void* d_out, int out_size, void* d_ws, size_t ws_size,
                              hipStream_t stream) {
  (void)n_in; (void)out_size; (void)d_ws; (void)ws_size;
  const float* rd = (const float*)d_in[0];
  float* out = (float*)d_out;
  int n = in_sizes[0] / 2;
  int grid = (n + 63) / 64;  // 64 points per 1-wave block
  sh_kernel<<<grid, 64, 0, stream>>>(rd, out, n);
}

// Round 6
// 188.963 us; speedup vs baseline: 1.1211x; 1.0241x over previous
//
#include <hip/hip_runtime.h>
#include <type_traits>

#define LMAX 24

typedef float f32x4 __attribute__((ext_vector_type(4)));

// ---------- compile-time normalization table K(l,m) ----------
constexpr double csqrt_(double x) {
  double y = x > 1.0 ? x : 1.0;
  for (int i = 0; i < 300; ++i) y = 0.5 * (y + x / y);
  return y;
}
constexpr double cfact_(int n) {
  double r = 1.0;
  for (int i = 2; i <= n; ++i) r *= (double)i;
  return r;
}
constexpr double PI_ = 3.14159265358979323846;

struct KTab {
  float k[LMAX][LMAX];
  constexpr KTab() : k{} {
    for (int l = 0; l < LMAX; ++l)
      for (int m = 0; m <= l; ++m)
        k[l][m] = (float)csqrt_((2.0 * l + 1.0) * cfact_(l - m) /
                                (4.0 * PI_ * cfact_(l + m)));
  }
};
constexpr KTab KT{};
constexpr float SQRT2_ = 1.41421356237309504880f;

// ---------- compile-time loop unroller ----------
template <int N, int I = 0, typename F>
__device__ __forceinline__ void static_for(F&& f) {
  if constexpr (I < N) {
    f(std::integral_constant<int, I>{});
    static_for<N, I + 1>(f);
  }
}

// One wave (64 threads) per block, 64 points per block. Staging buffer
// [64 points][64 j-values], row stride 65 dwords:
//   emit write bank  = (65*lane + j) % 32 = (lane + j) % 32      -> 2-way (free)
//   flush read bank  = (65*pp + 4c) % 32  = (4t + h + 4c) % 32   -> even 2-way
// A/B vs R5: chunk contiguity per point-row doubles 128B -> 256B; everything
// else identical. Tests the HBM page-locality theory of the 4.9 TB/s plateau.
#define CJ 64
#define STR 65

__global__ __launch_bounds__(64) void sh_kernel(const float* __restrict__ rd,
                                                float* __restrict__ out, int n) {
  __shared__ float lds[64 * STR];

  const int lane = threadIdx.x;
  const long long base_pt = (long long)blockIdx.x * 64;
  const long long my_pt = base_pt + lane;
  const int src = my_pt < n ? (int)my_pt : 0;
  const bool full = (base_pt + 64) <= (long long)n;  // wave-uniform

  const float2 p = reinterpret_cast<const float2*>(rd)[src];
  const float D2R = 0.017453292519943295f;
  float phi = p.x * D2R;
  float theta = (p.y + 90.0f) * D2R;
  float x = cosf(theta);
  float somx2 = sqrtf((1.0f - x) * (1.0f + x));

  // cos(m*phi), sin(m*phi) via Chebyshev recurrence (register arrays)
  float cm[LMAX], sm[LMAX];
  cm[0] = 1.0f; sm[0] = 0.0f;
  float c1, s1;
  __sincosf(phi, &s1, &c1);
  cm[1] = c1; sm[1] = s1;
  float twoc = 2.0f * c1;
#pragma unroll
  for (int m = 2; m < LMAX; ++m) {
    cm[m] = twoc * cm[m - 1] - cm[m - 2];
    sm[m] = twoc * sm[m - 1] - sm[m - 2];
  }

  float cur[LMAX], prev[LMAX];
  float pmm = 1.0f;

  float* const wptr = lds + lane * STR;  // this thread's staging row
  const float* const rbase = lds;

  // cooperative flush of chunk jc (64 j-values for all 64 points):
  // 16 passes; per pass 4 points x 16 lanes x 16B = 4 x 256B contiguous runs
  auto flush = [&](int jc) {
    __builtin_amdgcn_wave_barrier();
    const int h = lane >> 4;        // point sub-index within pass
    const int c = lane & 15;        // 16B column within the 256B chunk
    if (full) {
#pragma unroll
      for (int t = 0; t < 16; ++t) {
        int pp = t * 4 + h;
        int off = pp * STR + c * 4;
        f32x4 v = *reinterpret_cast<const f32x4*>(rbase + off);
        *reinterpret_cast<f32x4*>(out + (base_pt + pp) * (size_t)(LMAX * LMAX) +
                                  jc * CJ + c * 4) = v;
      }
    } else {
#pragma unroll
      for (int t = 0; t < 16; ++t) {
        int pp = t * 4 + h;
        int off = pp * STR + c * 4;
        f32x4 v = *reinterpret_cast<const f32x4*>(rbase + off);
        long long pt = base_pt + pp;
        if (pt < n) {
          *reinterpret_cast<f32x4*>(out + pt * (size_t)(LMAX * LMAX) +
                                    jc * CJ + c * 4) = v;
        }
      }
    }
    __builtin_amdgcn_wave_barrier();
  };

  static_for<LMAX>([&](auto LC) {
    constexpr int l = decltype(LC)::value;

    // advance recurrence state for all m < l  (gives P(l,m))
    const float ax = (float)(2 * l - 1) * x;
    static_for<l>([&](auto MC) {
      constexpr int m = decltype(MC)::value;
      constexpr float b = (float)(l + m - 1);
      constexpr float inv = 1.0f / (float)(l - m);
      float nxt = (ax * cur[m] - b * prev[m]) * inv;
      prev[m] = cur[m];
      cur[m] = nxt;
    });

    // init state for m = l:  P(l,l) = pmm,  prev = 0
    if constexpr (l > 0) {
      pmm = pmm * (-(float)(2 * l - 1)) * somx2;
    }
    cur[l] = pmm;
    prev[l] = 0.0f;

    // emit row l in j order (j = l*l + l + m, globally contiguous 0..575),
    // staging into LDS; flush every 64 values
    static_for<2 * l + 1>([&](auto KC) {
      constexpr int m = decltype(KC)::value - l;
      constexpr int am = m < 0 ? -m : m;
      constexpr int j = l * l + l + m;
      constexpr float C = (m == 0) ? KT.k[l][0] : SQRT2_ * KT.k[l][am];
      float y;
      if constexpr (m == 0) {
        y = C * cur[0];
      } else if constexpr (m > 0) {
        y = C * (cm[am] * cur[am]);
      } else {
        y = C * (sm[am] * cur[am]);
      }
      wptr[j & (CJ - 1)] = y;
      if constexpr ((j & (CJ - 1)) == CJ - 1) {
        flush(j >> 6);
      }
    });
  });
}

extern "C" void kernel_launch(void* const* d_in, const int* in_sizes, int n_in,
                              void* d_out, int out_size, void* d_ws, size_t ws_size,
                              hipStream_t stream) {
  (void)n_in; (void)out_size; (void)d_ws; (void)ws_size;
  const float* rd = (const float*)d_in[0];
  float* out = (float*)d_out;
  int n = in_sizes[0] / 2;
  int grid = (n + 63) / 64;  // 64 points per 1-wave block
  sh_kernel<<<grid, 64, 0, stream>>>(rd, out, n);
}

// Round 7
// 184.489 us; speedup vs baseline: 1.1483x; 1.0243x over previous
//
#include <hip/hip_runtime.h>
#include <type_traits>

#define LMAX 24

typedef float f32x4 __attribute__((ext_vector_type(4)));
typedef float f32x2 __attribute__((ext_vector_type(2)));

// ---------- compile-time normalization table K(l,m) ----------
constexpr double csqrt_(double x) {
  double y = x > 1.0 ? x : 1.0;
  for (int i = 0; i < 300; ++i) y = 0.5 * (y + x / y);
  return y;
}
constexpr double cfact_(int n) {
  double r = 1.0;
  for (int i = 2; i <= n; ++i) r *= (double)i;
  return r;
}
constexpr double PI_ = 3.14159265358979323846;

struct KTab {
  float k[LMAX][LMAX];
  constexpr KTab() : k{} {
    for (int l = 0; l < LMAX; ++l)
      for (int m = 0; m <= l; ++m)
        k[l][m] = (float)csqrt_((2.0 * l + 1.0) * cfact_(l - m) /
                                (4.0 * PI_ * cfact_(l + m)));
  }
};
constexpr KTab KT{};
constexpr float SQRT2_ = 1.41421356237309504880f;

// ---------- compile-time loop unroller ----------
template <int N, int I = 0, typename F>
__device__ __forceinline__ void static_for(F&& f) {
  if constexpr (I < N) {
    f(std::integral_constant<int, I>{});
    static_for<N, I + 1>(f);
  }
}

// One wave (64 threads) per block, 64 points per block. Staging buffer
// [64 points][32 j], row stride 34 dwords (136 B, 8B-aligned rows).
//   emit ds_write_b64 bank: (34L+jb)%32 = (2L+jb)%32 -> 4 dwords/bank = min
//   flush ds_read_b64 bank: (8t+2r+4q)%32            -> 4 lanes/bank  = min
// A/B vs R5/R6: DS write instructions halved (576 b32 -> 288 b64), all else
// identical. Tests whether DS-pipe occupancy (~51us/CU) is partially exposed.
#define CJ 32
#define STR 34

__global__ __launch_bounds__(64) void sh_kernel(const float* __restrict__ rd,
                                                float* __restrict__ out, int n) {
  __shared__ float lds[64 * STR];

  const int lane = threadIdx.x;
  const long long base_pt = (long long)blockIdx.x * 64;
  const long long my_pt = base_pt + lane;
  const int src = my_pt < n ? (int)my_pt : 0;
  const bool full = (base_pt + 64) <= (long long)n;  // wave-uniform

  const float2 p = reinterpret_cast<const float2*>(rd)[src];
  const float D2R = 0.017453292519943295f;
  float phi = p.x * D2R;
  float theta = (p.y + 90.0f) * D2R;
  float x = cosf(theta);
  float somx2 = sqrtf((1.0f - x) * (1.0f + x));

  // cos(m*phi), sin(m*phi) via Chebyshev recurrence (register arrays)
  float cm[LMAX], sm[LMAX];
  cm[0] = 1.0f; sm[0] = 0.0f;
  float c1, s1;
  __sincosf(phi, &s1, &c1);
  cm[1] = c1; sm[1] = s1;
  float twoc = 2.0f * c1;
#pragma unroll
  for (int m = 2; m < LMAX; ++m) {
    cm[m] = twoc * cm[m - 1] - cm[m - 2];
    sm[m] = twoc * sm[m - 1] - sm[m - 2];
  }

  float cur[LMAX], prev[LMAX];
  float pmm = 1.0f;
  float b0 = 0.f;  // pending even-j value of the current pair

  float* const wptr = lds + lane * STR;  // this thread's staging row
  const float* const rbase = lds;

  // cooperative flush of chunk jc (32 j-values for all 64 points):
  // 8 passes; per pass 8 rows x 8 lanes x 16B = 8 x 128B runs.
  // reads are 2x ds_read_b64 (rows are 8B- but not 16B-aligned).
  auto flush = [&](int jc) {
    __builtin_amdgcn_wave_barrier();
    const int r = lane >> 3;        // row sub-index within pass
    const int q = lane & 7;         // 16B column
    if (full) {
#pragma unroll
      for (int t = 0; t < 8; ++t) {
        int pp = t * 8 + r;
        int off = pp * STR + q * 4;
        f32x2 lo = *reinterpret_cast<const f32x2*>(rbase + off);
        f32x2 hi = *reinterpret_cast<const f32x2*>(rbase + off + 2);
        *reinterpret_cast<f32x4*>(out + (base_pt + pp) * (size_t)(LMAX * LMAX) +
                                  jc * CJ + q * 4) = f32x4{lo.x, lo.y, hi.x, hi.y};
      }
    } else {
#pragma unroll
      for (int t = 0; t < 8; ++t) {
        int pp = t * 8 + r;
        int off = pp * STR + q * 4;
        f32x2 lo = *reinterpret_cast<const f32x2*>(rbase + off);
        f32x2 hi = *reinterpret_cast<const f32x2*>(rbase + off + 2);
        long long pt = base_pt + pp;
        if (pt < n) {
          *reinterpret_cast<f32x4*>(out + pt * (size_t)(LMAX * LMAX) +
                                    jc * CJ + q * 4) = f32x4{lo.x, lo.y, hi.x, hi.y};
        }
      }
    }
    __builtin_amdgcn_wave_barrier();
  };

  static_for<LMAX>([&](auto LC) {
    constexpr int l = decltype(LC)::value;

    // advance recurrence state for all m < l  (gives P(l,m))
    const float ax = (float)(2 * l - 1) * x;
    static_for<l>([&](auto MC) {
      constexpr int m = decltype(MC)::value;
      constexpr float b = (float)(l + m - 1);
      constexpr float inv = 1.0f / (float)(l - m);
      float nxt = (ax * cur[m] - b * prev[m]) * inv;
      prev[m] = cur[m];
      cur[m] = nxt;
    });

    // init state for m = l:  P(l,l) = pmm,  prev = 0
    if constexpr (l > 0) {
      pmm = pmm * (-(float)(2 * l - 1)) * somx2;
    }
    cur[l] = pmm;
    prev[l] = 0.0f;

    // emit row l in j order (j = l*l + l + m, globally contiguous 0..575);
    // pair up consecutive j's -> ds_write_b64; flush every 32 values
    static_for<2 * l + 1>([&](auto KC) {
      constexpr int m = decltype(KC)::value - l;
      constexpr int am = m < 0 ? -m : m;
      constexpr int j = l * l + l + m;
      constexpr float C = (m == 0) ? KT.k[l][0] : SQRT2_ * KT.k[l][am];
      float y;
      if constexpr (m == 0) {
        y = C * cur[0];
      } else if constexpr (m > 0) {
        y = C * (cm[am] * cur[am]);
      } else {
        y = C * (sm[am] * cur[am]);
      }
      if constexpr ((j & 1) == 0) {
        b0 = y;
      } else {
        *reinterpret_cast<f32x2*>(wptr + ((j & (CJ - 1)) - 1)) = f32x2{b0, y};
      }
      if constexpr ((j & (CJ - 1)) == CJ - 1) {
        flush(j >> 5);
      }
    });
  });
}

extern "C" void kernel_launch(void* const* d_in, const int* in_sizes, int n_in,
                              void* d_out, int out_size, void* d_ws, size_t ws_size,
                              hipStream_t stream) {
  (void)n_in; (void)out_size; (void)d_ws; (void)ws_size;
  const float* rd = (const float*)d_in[0];
  float* out = (float*)d_out;
  int n = in_sizes[0] / 2;
  int grid = (n + 63) / 64;  // 64 points per 1-wave block
  sh_kernel<<<grid, 64, 0, stream>>>(rd, out, n);
}